// Round 5
// baseline (560.174 us; speedup 1.0000x reference)
//
#include <hip/hip_runtime.h>
#include <cstdint>
#include <cstddef>

typedef __attribute__((ext_vector_type(8))) short bf16x8;   // 8 bf16 in 4 VGPRs
typedef __attribute__((ext_vector_type(4))) float f32x4;

__device__ __forceinline__ unsigned short f2bf(float f) {
  union { float f; unsigned u; } v; v.f = f;
  unsigned r = v.u + 0x7FFFu + ((v.u >> 16) & 1u);   // round-to-nearest-even
  return (unsigned short)(r >> 16);
}

#define GLL(gp, lp) __builtin_amdgcn_global_load_lds( \
    (const __attribute__((address_space(1))) void*)(gp), \
    (__attribute__((address_space(3))) void*)(lp), 16, 0, 0)

#define FENCE() __builtin_amdgcn_sched_barrier(0)

#define BARRIER() do { \
  asm volatile("" ::: "memory"); \
  __builtin_amdgcn_sched_barrier(0); \
  __builtin_amdgcn_s_barrier(); \
  __builtin_amdgcn_sched_barrier(0); \
  asm volatile("" ::: "memory"); } while (0)

// ---------------- elementwise fp32 -> bf16 ----------------
__global__ void cvt_x_kernel(const float* __restrict__ x, unsigned short* __restrict__ xb, int n4) {
  int i = blockIdx.x * blockDim.x + threadIdx.x;
  if (i >= n4) return;
  const float4 v = reinterpret_cast<const float4*>(x)[i];
  ushort4 o;
  o.x = f2bf(v.x); o.y = f2bf(v.y); o.z = f2bf(v.z); o.w = f2bf(v.w);
  reinterpret_cast<ushort4*>(xb)[i] = o;
}

// ---------------- transpose fp32 (K x N) -> bf16 (N x K) ----------------
__global__ void transpose_kernel(const float* __restrict__ src, unsigned short* __restrict__ dst,
                                 int K, int N) {
  __shared__ float t[32][33];
  const int tx = threadIdx.x, ty = threadIdx.y;
  const int n0 = blockIdx.x * 32, k0 = blockIdx.y * 32;
#pragma unroll
  for (int i = 0; i < 4; ++i)
    t[ty + i * 8][tx] = src[(size_t)(k0 + ty + i * 8) * N + n0 + tx];
  __syncthreads();
#pragma unroll
  for (int i = 0; i < 4; ++i)
    dst[(size_t)(n0 + ty + i * 8) * K + k0 + tx] = f2bf(t[tx][ty + i * 8]);
}

// ---------------- 256x256 8-phase bf16 MFMA GEMM (T1+T2+T3+T4+T5) ----------------
// A: M x K row-major bf16. B: N x K row-major bf16 (weights pre-transposed).
// 512 threads = 8 waves (2M x 4N); per-wave 128x64 C-tile; BK=64; LDS 128 KB.
// Swizzle: 16B chunk c of row r stored at slot c ^ (r&7); staged via pre-swizzled
// global source + linear global_load_lds dest; ds_read applies the same XOR.
// Stage stream runs 7 half-tiles ahead; one vmcnt(6) per K-tile (tail: 0).
//
// CRITICAL (R4 fix): a stage "half" must equal the READ phase's row set, which
// is INTERLEAVED across the two wm spans: READA(.,h) reads rows
// {h*64..h*64+63} U {128+h*64..+63}. stageA now stages exactly that set
// (R3/R4 bug: contiguous halves meant stageA(t+2,0)@ph1 overwrote rows 64..127
// still read by READA(a,1)@ph2 -> deterministic corruption). stageB was
// already interleaved to match READB.

#define READA(DST, MQ) do { \
  _Pragma("unroll") for (int i_ = 0; i_ < 4; ++i_) { \
    const int row_ = wm * 128 + (MQ) * 64 + i_ * 16 + q16; \
    _Pragma("unroll") for (int kh_ = 0; kh_ < 2; ++kh_) \
      DST[i_][kh_] = *(const bf16x8*)(Ab + row_ * 128 + ((((kh_ << 2) | g) ^ (row_ & 7)) << 4)); \
  } } while (0)

#define READB(DST, NQ) do { \
  _Pragma("unroll") for (int j_ = 0; j_ < 2; ++j_) { \
    const int row_ = wn * 64 + (NQ) * 32 + j_ * 16 + q16; \
    _Pragma("unroll") for (int kh_ = 0; kh_ < 2; ++kh_) \
      DST[j_][kh_] = *(const bf16x8*)(Bb + row_ * 128 + ((((kh_ << 2) | g) ^ (row_ & 7)) << 4)); \
  } } while (0)

#define MFMAPH(AR, BR, MB, NB) do { \
  __builtin_amdgcn_s_setprio(1); \
  _Pragma("unroll") for (int i_ = 0; i_ < 4; ++i_) \
  _Pragma("unroll") for (int j_ = 0; j_ < 2; ++j_) \
  _Pragma("unroll") for (int kh_ = 0; kh_ < 2; ++kh_) \
    acc[(MB) + i_][(NB) + j_] = __builtin_amdgcn_mfma_f32_16x16x32_bf16( \
        AR[i_][kh_], BR[j_][kh_], acc[(MB) + i_][(NB) + j_], 0, 0, 0); \
  __builtin_amdgcn_s_setprio(0); \
  } while (0)

template <int EPI>
__global__ __launch_bounds__(512, 2) void gemm8_kernel(
    const unsigned short* __restrict__ Ag, const unsigned short* __restrict__ Bg,
    int K, int N, int mtMask, int mtShift,
    float* __restrict__ yout,
    const float* __restrict__ fcos, const float* __restrict__ fsin,
    unsigned short* __restrict__ q_ws, unsigned short* __restrict__ k_ws,
    unsigned short* __restrict__ vT_ws,
    float* __restrict__ k_out, float* __restrict__ v_out) {
  __shared__ unsigned short Asb[2][16384];   // [buf][256 rows][64 cols]
  __shared__ unsigned short Bsb[2][16384];

  const int tid = threadIdx.x;
  const int w = tid >> 6, lane = tid & 63;
  const int wm = w >> 2, wn = w & 3;
  const int g = lane >> 4, q16 = lane & 15;
  const int ls = lane >> 3;                      // row within 8-row stage slab
  const int lc = ((lane & 7) ^ ls) << 3;         // pre-swizzled source chunk (elems)

  // T1: bijective XCD swizzle (gridDim.x % 8 == 0 by construction)
  const int cpx = (int)gridDim.x >> 3;
  int bid = (int)blockIdx.x;
  bid = (bid & 7) * cpx + (bid >> 3);
  const int bm = bid & mtMask;
  const int bn = bid >> mtShift;
  const int m0 = bm << 8, n0 = bn << 8;
  const int NT = K >> 6;

  auto stageA = [&](int tile, int half) {
    if (tile >= NT) return;
    // interleaved half: rows {p*128 + half*64 + s*16 .. +15}, p=w>>2, s=w&3
    const int rowbase = (w >> 2) * 128 + half * 64 + (w & 3) * 16;
    unsigned short* base = &Asb[tile & 1][rowbase * 64];
    const unsigned short* src = Ag + (size_t)(m0 + rowbase + ls) * K + tile * 64 + lc;
#pragma unroll
    for (int i = 0; i < 2; ++i)
      GLL(src + (size_t)i * 8 * K, base + i * 8 * 64);
  };
  auto stageB = [&](int tile, int half) {
    if (tile >= NT) return;
#pragma unroll
    for (int i = 0; i < 2; ++i) {
      const int seq = w * 2 + i;
      const int rowbase = (seq >> 2) * 64 + half * 32 + (seq & 3) * 8;
      GLL(Bg + (size_t)(n0 + rowbase + ls) * K + tile * 64 + lc,
          &Bsb[tile & 1][rowbase * 64]);
    }
  };

  f32x4 acc[8][4] = {};
  bf16x8 a[4][2], b0[2][2], b1[2][2];

  // prologue: tile0 full + tile1 {Ah0,Bh0,Bh1}; FENCE pins GLL issue order
  stageA(0, 0); FENCE();
  stageB(0, 0); FENCE();
  stageB(0, 1); FENCE();
  stageA(0, 1); FENCE();
  stageA(1, 0); FENCE();
  stageB(1, 0); FENCE();
  stageB(1, 1); FENCE();
  asm volatile("s_waitcnt vmcnt(6)" ::: "memory");
  BARRIER();

  for (int t = 0; t < NT; ++t) {
    const char* Ab = (const char*)Asb + (t & 1) * 32768;
    const char* Bb = (const char*)Bsb + (t & 1) * 32768;
    // ph0: Q(mq0,nq0) — reads A-set0, B-set0 (b0 regs held to ph3)
    READA(a, 0); READB(b0, 0);
    stageA(t + 1, 1);                            // buf^1 A-set1 (last read ph2 of t-1)
    BARRIER();
    MFMAPH(a, b0, 0, 0);
    BARRIER();
    // ph1: Q(mq0,nq1) — reads B-set1
    READB(b1, 1);
    stageA(t + 2, 0);                            // this buf A-set0 (died ph0)
    BARRIER();
    MFMAPH(a, b1, 0, 2);
    BARRIER();
    // ph2: Q(mq1,nq1) — reads A-set1
    READA(a, 1);
    stageB(t + 2, 0);                            // this buf B-set0 (died ph0)
    BARRIER();
    MFMAPH(a, b1, 4, 2);
    BARRIER();
    // ph3: Q(mq1,nq0) — no LDS reads (a, b0 in regs)
    stageB(t + 2, 1);                            // this buf B-set1 (died ph1)
    if (t < NT - 2) { asm volatile("s_waitcnt vmcnt(6)" ::: "memory"); }
    else           { asm volatile("s_waitcnt vmcnt(0)" ::: "memory"); }
    BARRIER();
    MFMAPH(a, b0, 4, 0);
    BARRIER();
  }

  // ---- epilogue ----  C/D: col = q16, row = g*4 + r
  const int region = n0 >> 11;                   // EPI==1: 0=q,1=k,2=v
#pragma unroll
  for (int mi = 0; mi < 8; ++mi) {
#pragma unroll
    for (int nj = 0; nj < 4; ++nj) {
#pragma unroll
      for (int r = 0; r < 4; ++r) {
        const int m = m0 + wm * 128 + mi * 16 + g * 4 + r;
        const int n = n0 + wn * 64 + nj * 16 + q16;
        const float val = acc[mi][nj][r];
        if (EPI == 0) {
          yout[(size_t)m * N + n] = val;
        } else {
          const int h = (n >> 7) & 15;
          const int b = m >> 11, tt = m & 2047;
          const int dcol = n & 127;
          const size_t idx = ((size_t)((b * 16 + h) * 2048 + tt)) * 128 + dcol;
          if (region == 2) {
            v_out[idx] = val;
            vT_ws[((size_t)(b * 16 + h) * 128 + dcol) * 2048 + tt] = f2bf(val);
          } else {
            const int fi = dcol >> 1;
            const float c = fcos[tt * 64 + fi];
            const float s = fsin[tt * 64 + fi];
            const float part = __shfl_xor(val, 1);
            const float ro = (dcol & 1) ? (part * s + val * c) : (val * c - part * s);
            if (region == 0) {
              q_ws[idx] = f2bf(ro * 0.08838834764831845f);   // fold 1/sqrt(hd)
            } else {
              k_out[idx] = ro;
              k_ws[idx] = f2bf(ro);
            }
          }
        }
      }
    }
  }
}

// ---------------- flash attention (unchanged, R2-verified) ----------------
__global__ __launch_bounds__(256, 2) void attn_kernel(
    const unsigned short* __restrict__ q_ws,
    const unsigned short* __restrict__ k_ws,
    const unsigned short* __restrict__ vT_ws,
    unsigned short* __restrict__ attnout) {
  __shared__ unsigned short Kl[2][64 * 128];    // [key][d], chunk16 ^= (key&7)
  __shared__ unsigned short Vl[2][128 * 64];    // [d][key], chunk16 ^= (d&7)
  __shared__ unsigned short Pl[4][2][16 * 64];  // per-wave per-qsub, byte ^= (q&7)<<4

  const int tid = threadIdx.x;
  const int w = tid >> 6, lane = tid & 63;
  const int g = lane >> 4, q16 = lane & 15;
  const int bh = blockIdx.x;
  const int qt = 15 - (int)blockIdx.y;          // heaviest q-tiles first
  const int b = bh >> 4, h = bh & 15;
  const int qbase = qt * 128;
  const int qb = qbase + w * 32;
  const size_t kvbase = (size_t)bh * 2048 * 128;

  const int krow_l = lane >> 4, kchunk = lane & 15;
  const int vrow_l = lane >> 3, vchunk = lane & 7;

  bf16x8 qf[2][4];
#pragma unroll
  for (int qs = 0; qs < 2; ++qs)
#pragma unroll
    for (int c = 0; c < 4; ++c)
      qf[qs][c] = *(const bf16x8*)&q_ws[kvbase + (size_t)(qb + qs * 16 + q16) * 128 + c * 32 + g * 8];

  f32x4 acc[2][8] = {};
  float mrun[2] = {-1e30f, -1e30f};
  float lrun[2] = {0.f, 0.f};

  const int nt = (qt + 1) * 2;

  auto stageK = [&](int buf, int kt) {
#pragma unroll
    for (int i = 0; i < 4; ++i) {
      const int slab = w * 4 + i;
      const int krow = slab * 4 + krow_l;
      GLL(k_ws + kvbase + (size_t)(kt + krow) * 128 + ((kchunk ^ (krow & 7)) << 3),
          ((unsigned short*)Kl[buf]) + slab * 512);
    }
  };
  auto stageV = [&](int buf, int kt) {
#pragma unroll
    for (int i = 0; i < 4; ++i) {
      const int slab = w * 4 + i;
      const int d = slab * 8 + vrow_l;
      GLL(vT_ws + kvbase + (size_t)d * 2048 + kt + ((vchunk ^ (d & 7)) << 3),
          ((unsigned short*)Vl[buf]) + slab * 512);
    }
  };

  stageK(0, 0); stageV(0, 0);
  int cur = 0;
  for (int it = 0; it < nt; ++it) {
    const int kt = it * 64;
    __syncthreads();
    if (it + 1 < nt) { stageK(cur ^ 1, kt + 64); stageV(cur ^ 1, kt + 64); }

    if (kt <= qb + 31) {
      f32x4 s[2][4];
#pragma unroll
      for (int qs = 0; qs < 2; ++qs)
#pragma unroll
        for (int t = 0; t < 4; ++t) s[qs][t] = f32x4{0.f, 0.f, 0.f, 0.f};
#pragma unroll
      for (int t = 0; t < 4; ++t) {
        const int key = t * 16 + q16;
#pragma unroll
        for (int c = 0; c < 4; ++c) {
          bf16x8 kf = *(const bf16x8*)&Kl[cur][key * 128 + (((c * 4 + g) ^ (key & 7)) << 3)];
          s[0][t] = __builtin_amdgcn_mfma_f32_16x16x32_bf16(kf, qf[0][c], s[0][t], 0, 0, 0);
          s[1][t] = __builtin_amdgcn_mfma_f32_16x16x32_bf16(kf, qf[1][c], s[1][t], 0, 0, 0);
        }
      }

#pragma unroll
      for (int qs = 0; qs < 2; ++qs) {
        const int qrow = qb + qs * 16 + q16;
        if (kt + 64 > qb + qs * 16) {
#pragma unroll
          for (int t = 0; t < 4; ++t)
#pragma unroll
            for (int r = 0; r < 4; ++r)
              if (kt + t * 16 + g * 4 + r > qrow) s[qs][t][r] = -1e30f;
        }
        float tm = s[qs][0][0];
#pragma unroll
        for (int t = 0; t < 4; ++t)
#pragma unroll
          for (int r = 0; r < 4; ++r) tm = fmaxf(tm, s[qs][t][r]);
        tm = fmaxf(tm, __shfl_xor(tm, 16));
        tm = fmaxf(tm, __shfl_xor(tm, 32));
        if (__any(tm > mrun[qs] + 8.0f)) {             // T13 defer-max
          const float mnew = fmaxf(mrun[qs], tm);
          const float fac = __expf(mrun[qs] - mnew);
          lrun[qs] *= fac;
          mrun[qs] = mnew;
          float fr0 = __shfl(fac, g * 4 + 0), fr1 = __shfl(fac, g * 4 + 1);
          float fr2 = __shfl(fac, g * 4 + 2), fr3 = __shfl(fac, g * 4 + 3);
#pragma unroll
          for (int n = 0; n < 8; ++n) {
            acc[qs][n][0] *= fr0; acc[qs][n][1] *= fr1;
            acc[qs][n][2] *= fr2; acc[qs][n][3] *= fr3;
          }
        }
        float ps = 0.f;
        unsigned pk[8];
#pragma unroll
        for (int t = 0; t < 4; ++t) {
          const float p0 = __expf(s[qs][t][0] - mrun[qs]);
          const float p1 = __expf(s[qs][t][1] - mrun[qs]);
          const float p2 = __expf(s[qs][t][2] - mrun[qs]);
          const float p3 = __expf(s[qs][t][3] - mrun[qs]);
          ps += (p0 + p1) + (p2 + p3);
          pk[t * 2]     = (unsigned)f2bf(p0) | ((unsigned)f2bf(p1) << 16);
          pk[t * 2 + 1] = (unsigned)f2bf(p2) | ((unsigned)f2bf(p3) << 16);
        }
        ps += __shfl_xor(ps, 16);
        ps += __shfl_xor(ps, 32);
        lrun[qs] += ps;
#pragma unroll
        for (int t = 0; t < 4; ++t) {
          const unsigned byteoff = (unsigned)(q16 * 128) +
              (((unsigned)(t * 32 + g * 8)) ^ ((unsigned)(q16 & 7) << 4));
          *(uint2*)((char*)&Pl[w][qs][0] + byteoff) = make_uint2(pk[t * 2], pk[t * 2 + 1]);
        }
      }

      asm volatile("s_waitcnt lgkmcnt(0)" ::: "memory");
      __builtin_amdgcn_sched_barrier(0);
#pragma unroll
      for (int ks = 0; ks < 2; ++ks) {
        const unsigned pcol = ((unsigned)(ks * 64 + g * 16)) ^ ((unsigned)(q16 & 7) << 4);
        bf16x8 pa0 = *(const bf16x8*)((char*)&Pl[w][0][0] + q16 * 128 + pcol);
        bf16x8 pa1 = *(const bf16x8*)((char*)&Pl[w][1][0] + q16 * 128 + pcol);
#pragma unroll
        for (int n = 0; n < 8; ++n) {
          const int d = n * 16 + q16;
          bf16x8 vf = *(const bf16x8*)&Vl[cur][d * 64 + (((ks * 4 + g) ^ (d & 7)) << 3)];
          acc[0][n] = __builtin_amdgcn_mfma_f32_16x16x32_bf16(pa0, vf, acc[0][n], 0, 0, 0);
          acc[1][n] = __builtin_amdgcn_mfma_f32_16x16x32_bf16(pa1, vf, acc[1][n], 0, 0, 0);
        }
      }
    }
    cur ^= 1;
  }

#pragma unroll
  for (int qs = 0; qs < 2; ++qs) {
    float rl[4];
#pragma unroll
    for (int r = 0; r < 4; ++r) rl[r] = 1.0f / __shfl(lrun[qs], g * 4 + r);
#pragma unroll
    for (int n = 0; n < 8; ++n) {
#pragma unroll
      for (int r = 0; r < 4; ++r) {
        const int q = qb + qs * 16 + g * 4 + r;
        const int d = n * 16 + q16;
        attnout[((size_t)(b * 2048 + q)) * 2048 + h * 128 + d] = f2bf(acc[qs][n][r] * rl[r]);
      }
    }
  }
}

extern "C" void kernel_launch(void* const* d_in, const int* in_sizes, int n_in,
                              void* d_out, int out_size, void* d_ws, size_t ws_size,
                              hipStream_t stream) {
  (void)in_sizes; (void)n_in; (void)out_size; (void)ws_size;
  const float* x    = (const float*)d_in[0];
  const float* fcos = (const float*)d_in[1];
  const float* fsin = (const float*)d_in[2];
  const float* Wqkv = (const float*)d_in[3];
  const float* Wout = (const float*)d_in[4];

  float* out   = (float*)d_out;
  float* y_out = out;
  float* k_out = out + (size_t)16777216;          // B*T*C
  float* v_out = out + (size_t)33554432;

  unsigned short* xb      = (unsigned short*)d_ws;     // 8192 x 2048
  unsigned short* wqkvT   = xb + 16777216;             // 6144 x 2048
  unsigned short* woutT   = wqkvT + 12582912;          // 2048 x 2048
  unsigned short* q_ws    = woutT + 4194304;           // (B,H,T,hd) pre-scaled
  unsigned short* k_ws    = q_ws + 16777216;           // (B,H,T,hd)
  unsigned short* vT_ws   = k_ws + 16777216;           // (B,H,hd,T)
  unsigned short* attnout = xb;                        // alias: x consumed by then

  cvt_x_kernel<<<16384, 256, 0, stream>>>(x, xb, 4194304);
  transpose_kernel<<<dim3(192, 64), dim3(32, 8), 0, stream>>>(Wqkv, wqkvT, 2048, 6144);
  transpose_kernel<<<dim3(64, 64), dim3(32, 8), 0, stream>>>(Wout, woutT, 2048, 2048);

  // GEMM1: 8192 x 6144 x 2048, fused RoPE/qkv epilogue. Grid 32x24=768 (%8==0).
  gemm8_kernel<1><<<768, 512, 0, stream>>>(
      xb, wqkvT, 2048, 6144, 31, 5,
      nullptr, fcos, fsin, q_ws, k_ws, vT_ws, k_out, v_out);

  attn_kernel<<<dim3(64, 16), 256, 0, stream>>>(q_ws, k_ws, vT_ws, attnout);

  // GEMM2: 8192 x 2048 x 2048 -> y. Grid 32x8=256 (%8==0).
  gemm8_kernel<0><<<256, 512, 0, stream>>>(
      attnout, woutT, 2048, 2048, 31, 5,
      y_out, nullptr, nullptr, nullptr, nullptr, nullptr, nullptr, nullptr);
}

// Round 6
// 545.068 us; speedup vs baseline: 1.0277x; 1.0277x over previous
//
#include <hip/hip_runtime.h>
#include <cstdint>
#include <cstddef>

typedef __attribute__((ext_vector_type(8))) short bf16x8;   // 8 bf16 in 4 VGPRs
typedef __attribute__((ext_vector_type(4))) float f32x4;

__device__ __forceinline__ unsigned short f2bf(float f) {
  union { float f; unsigned u; } v; v.f = f;
  unsigned r = v.u + 0x7FFFu + ((v.u >> 16) & 1u);   // round-to-nearest-even
  return (unsigned short)(r >> 16);
}

#define GLL(gp, lp) __builtin_amdgcn_global_load_lds( \
    (const __attribute__((address_space(1))) void*)(gp), \
    (__attribute__((address_space(3))) void*)(lp), 16, 0, 0)

#define FENCE() __builtin_amdgcn_sched_barrier(0)

// Bare barrier: NO asm memory clobbers. R5 lesson: asm volatile(""::: "memory")
// is modeled as "may read all memory" -> waitcnt pass emits s_waitcnt
// vmcnt(0) lgkmcnt(0) before it -> drains the GLL pipeline at EVERY phase
// barrier (m218 "drain-0" regime, -38-73%). sched_barrier(0) pins MIR motion.
#define BARRIER() do { \
  __builtin_amdgcn_sched_barrier(0); \
  __builtin_amdgcn_s_barrier(); \
  __builtin_amdgcn_sched_barrier(0); } while (0)

#define WAIT_LGKM0() do { \
  asm volatile("s_waitcnt lgkmcnt(0)"); \
  __builtin_amdgcn_sched_barrier(0); } while (0)

#define WAIT_VM(N) do { \
  asm volatile("s_waitcnt vmcnt(" #N ")"); \
  __builtin_amdgcn_sched_barrier(0); } while (0)

// ---------------- elementwise fp32 -> bf16 ----------------
__global__ void cvt_x_kernel(const float* __restrict__ x, unsigned short* __restrict__ xb, int n4) {
  int i = blockIdx.x * blockDim.x + threadIdx.x;
  if (i >= n4) return;
  const float4 v = reinterpret_cast<const float4*>(x)[i];
  ushort4 o;
  o.x = f2bf(v.x); o.y = f2bf(v.y); o.z = f2bf(v.z); o.w = f2bf(v.w);
  reinterpret_cast<ushort4*>(xb)[i] = o;
}

// ---------------- transpose fp32 (K x N) -> bf16 (N x K) ----------------
__global__ void transpose_kernel(const float* __restrict__ src, unsigned short* __restrict__ dst,
                                 int K, int N) {
  __shared__ float t[32][33];
  const int tx = threadIdx.x, ty = threadIdx.y;
  const int n0 = blockIdx.x * 32, k0 = blockIdx.y * 32;
#pragma unroll
  for (int i = 0; i < 4; ++i)
    t[ty + i * 8][tx] = src[(size_t)(k0 + ty + i * 8) * N + n0 + tx];
  __syncthreads();
#pragma unroll
  for (int i = 0; i < 4; ++i)
    dst[(size_t)(n0 + ty + i * 8) * K + k0 + tx] = f2bf(t[tx][ty + i * 8]);
}

// ---------------- 256x256 8-phase bf16 MFMA GEMM (T1+T2+T3+T4+T5) ----------------
// A: M x K row-major bf16. B: N x K row-major bf16 (weights pre-transposed).
// 512 threads = 8 waves (2M x 4N); per-wave 128x64 C-tile; BK=64; LDS 128 KB.
// Swizzle: 16B chunk c of row r stored at slot c ^ (r&7) (both-sides: pre-swizzled
// global source + linear GLL dest + swizzled ds_read).
// Stage stream runs 7 half-tiles ahead; one vmcnt(6) per K-tile (tail: 0).
// Stage "half" == READ phase's row set (interleaved across wm spans) — R4 fix.

#define READA(DST, MQ) do { \
  _Pragma("unroll") for (int i_ = 0; i_ < 4; ++i_) { \
    const int row_ = wm * 128 + (MQ) * 64 + i_ * 16 + q16; \
    _Pragma("unroll") for (int kh_ = 0; kh_ < 2; ++kh_) \
      DST[i_][kh_] = *(const bf16x8*)(Ab + row_ * 128 + ((((kh_ << 2) | g) ^ (row_ & 7)) << 4)); \
  } } while (0)

#define READB(DST, NQ) do { \
  _Pragma("unroll") for (int j_ = 0; j_ < 2; ++j_) { \
    const int row_ = wn * 64 + (NQ) * 32 + j_ * 16 + q16; \
    _Pragma("unroll") for (int kh_ = 0; kh_ < 2; ++kh_) \
      DST[j_][kh_] = *(const bf16x8*)(Bb + row_ * 128 + ((((kh_ << 2) | g) ^ (row_ & 7)) << 4)); \
  } } while (0)

#define MFMAPH(AR, BR, MB, NB) do { \
  __builtin_amdgcn_s_setprio(1); \
  _Pragma("unroll") for (int i_ = 0; i_ < 4; ++i_) \
  _Pragma("unroll") for (int j_ = 0; j_ < 2; ++j_) \
  _Pragma("unroll") for (int kh_ = 0; kh_ < 2; ++kh_) \
    acc[(MB) + i_][(NB) + j_] = __builtin_amdgcn_mfma_f32_16x16x32_bf16( \
        AR[i_][kh_], BR[j_][kh_], acc[(MB) + i_][(NB) + j_], 0, 0, 0); \
  __builtin_amdgcn_s_setprio(0); \
  } while (0)

template <int EPI>
__global__ __launch_bounds__(512, 2) void gemm8_kernel(
    const unsigned short* __restrict__ Ag, const unsigned short* __restrict__ Bg,
    int K, int N, int mtMask, int mtShift,
    float* __restrict__ yout,
    const float* __restrict__ fcos, const float* __restrict__ fsin,
    unsigned short* __restrict__ q_ws, unsigned short* __restrict__ k_ws,
    unsigned short* __restrict__ vT_ws,
    float* __restrict__ k_out, float* __restrict__ v_out) {
  __shared__ unsigned short Asb[2][16384];   // [buf][256 rows][64 cols]
  __shared__ unsigned short Bsb[2][16384];

  const int tid = threadIdx.x;
  const int w = tid >> 6, lane = tid & 63;
  const int wm = w >> 2, wn = w & 3;
  const int g = lane >> 4, q16 = lane & 15;
  const int ls = lane >> 3;                      // row within 8-row stage slab
  const int lc = ((lane & 7) ^ ls) << 3;         // pre-swizzled source chunk (elems)

  // T1: bijective XCD swizzle (gridDim.x % 8 == 0 by construction)
  const int cpx = (int)gridDim.x >> 3;
  int bid = (int)blockIdx.x;
  bid = (bid & 7) * cpx + (bid >> 3);
  const int bm = bid & mtMask;
  const int bn = bid >> mtShift;
  const int m0 = bm << 8, n0 = bn << 8;
  const int NT = K >> 6;

  auto stageA = [&](int tile, int half) {
    if (tile >= NT) return;
    // interleaved half: rows {p*128 + half*64 + s*16 .. +15}, p=w>>2, s=w&3
    const int rowbase = (w >> 2) * 128 + half * 64 + (w & 3) * 16;
    unsigned short* base = &Asb[tile & 1][rowbase * 64];
    const unsigned short* src = Ag + (size_t)(m0 + rowbase + ls) * K + tile * 64 + lc;
#pragma unroll
    for (int i = 0; i < 2; ++i)
      GLL(src + (size_t)i * 8 * K, base + i * 8 * 64);
  };
  auto stageB = [&](int tile, int half) {
    if (tile >= NT) return;
#pragma unroll
    for (int i = 0; i < 2; ++i) {
      const int seq = w * 2 + i;
      const int rowbase = (seq >> 2) * 64 + half * 32 + (seq & 3) * 8;
      GLL(Bg + (size_t)(n0 + rowbase + ls) * K + tile * 64 + lc,
          &Bsb[tile & 1][rowbase * 64]);
    }
  };

  f32x4 acc[8][4] = {};
  bf16x8 a[4][2], b0[2][2], b1[2][2];

  // prologue: tile0 full + tile1 {Ah0,Bh0,Bh1}; FENCE pins GLL issue order
  stageA(0, 0); FENCE();
  stageB(0, 0); FENCE();
  stageB(0, 1); FENCE();
  stageA(0, 1); FENCE();
  stageA(1, 0); FENCE();
  stageB(1, 0); FENCE();
  stageB(1, 1); FENCE();
  WAIT_VM(6);
  BARRIER();

  for (int t = 0; t < NT; ++t) {
    const char* Ab = (const char*)Asb + (t & 1) * 32768;
    const char* Bb = (const char*)Bsb + (t & 1) * 32768;
    // ph0: Q(mq0,nq0) — reads A-set0, B-set0 (b0 regs held to ph3)
    READA(a, 0); READB(b0, 0);
    stageA(t + 1, 1);                            // buf^1 A-set1 (last read ph2 of t-1)
    BARRIER();
    WAIT_LGKM0();
    MFMAPH(a, b0, 0, 0);
    BARRIER();
    // ph1: Q(mq0,nq1) — reads B-set1
    READB(b1, 1);
    stageA(t + 2, 0);                            // this buf A-set0 (died ph0)
    BARRIER();
    WAIT_LGKM0();
    MFMAPH(a, b1, 0, 2);
    BARRIER();
    // ph2: Q(mq1,nq1) — reads A-set1
    READA(a, 1);
    stageB(t + 2, 0);                            // this buf B-set0 (died ph0)
    BARRIER();
    WAIT_LGKM0();
    MFMAPH(a, b1, 4, 2);
    BARRIER();
    // ph3: Q(mq1,nq0) — no LDS reads (a, b0 in regs)
    stageB(t + 2, 1);                            // this buf B-set1 (died ph1)
    if (t < NT - 2) { WAIT_VM(6); }
    else           { WAIT_VM(0); }
    BARRIER();
    MFMAPH(a, b0, 4, 0);
    BARRIER();
  }

  // ---- epilogue ----  C/D: col = q16, row = g*4 + r
  const int region = n0 >> 11;                   // EPI==1: 0=q,1=k,2=v
#pragma unroll
  for (int mi = 0; mi < 8; ++mi) {
#pragma unroll
    for (int nj = 0; nj < 4; ++nj) {
#pragma unroll
      for (int r = 0; r < 4; ++r) {
        const int m = m0 + wm * 128 + mi * 16 + g * 4 + r;
        const int n = n0 + wn * 64 + nj * 16 + q16;
        const float val = acc[mi][nj][r];
        if (EPI == 0) {
          yout[(size_t)m * N + n] = val;
        } else {
          const int h = (n >> 7) & 15;
          const int b = m >> 11, tt = m & 2047;
          const int dcol = n & 127;
          const size_t idx = ((size_t)((b * 16 + h) * 2048 + tt)) * 128 + dcol;
          if (region == 2) {
            v_out[idx] = val;
            vT_ws[((size_t)(b * 16 + h) * 128 + dcol) * 2048 + tt] = f2bf(val);
          } else {
            const int fi = dcol >> 1;
            const float c = fcos[tt * 64 + fi];
            const float s = fsin[tt * 64 + fi];
            const float part = __shfl_xor(val, 1);
            const float ro = (dcol & 1) ? (part * s + val * c) : (val * c - part * s);
            if (region == 0) {
              q_ws[idx] = f2bf(ro * 0.08838834764831845f);   // fold 1/sqrt(hd)
            } else {
              k_out[idx] = ro;
              k_ws[idx] = f2bf(ro);
            }
          }
        }
      }
    }
  }
}

// ---------------- flash attention (unchanged, R2-verified) ----------------
__global__ __launch_bounds__(256, 2) void attn_kernel(
    const unsigned short* __restrict__ q_ws,
    const unsigned short* __restrict__ k_ws,
    const unsigned short* __restrict__ vT_ws,
    unsigned short* __restrict__ attnout) {
  __shared__ unsigned short Kl[2][64 * 128];    // [key][d], chunk16 ^= (key&7)
  __shared__ unsigned short Vl[2][128 * 64];    // [d][key], chunk16 ^= (d&7)
  __shared__ unsigned short Pl[4][2][16 * 64];  // per-wave per-qsub, byte ^= (q&7)<<4

  const int tid = threadIdx.x;
  const int w = tid >> 6, lane = tid & 63;
  const int g = lane >> 4, q16 = lane & 15;
  const int bh = blockIdx.x;
  const int qt = 15 - (int)blockIdx.y;          // heaviest q-tiles first
  const int b = bh >> 4, h = bh & 15;
  const int qbase = qt * 128;
  const int qb = qbase + w * 32;
  const size_t kvbase = (size_t)bh * 2048 * 128;

  const int krow_l = lane >> 4, kchunk = lane & 15;
  const int vrow_l = lane >> 3, vchunk = lane & 7;

  bf16x8 qf[2][4];
#pragma unroll
  for (int qs = 0; qs < 2; ++qs)
#pragma unroll
    for (int c = 0; c < 4; ++c)
      qf[qs][c] = *(const bf16x8*)&q_ws[kvbase + (size_t)(qb + qs * 16 + q16) * 128 + c * 32 + g * 8];

  f32x4 acc[2][8] = {};
  float mrun[2] = {-1e30f, -1e30f};
  float lrun[2] = {0.f, 0.f};

  const int nt = (qt + 1) * 2;

  auto stageK = [&](int buf, int kt) {
#pragma unroll
    for (int i = 0; i < 4; ++i) {
      const int slab = w * 4 + i;
      const int krow = slab * 4 + krow_l;
      GLL(k_ws + kvbase + (size_t)(kt + krow) * 128 + ((kchunk ^ (krow & 7)) << 3),
          ((unsigned short*)Kl[buf]) + slab * 512);
    }
  };
  auto stageV = [&](int buf, int kt) {
#pragma unroll
    for (int i = 0; i < 4; ++i) {
      const int slab = w * 4 + i;
      const int d = slab * 8 + vrow_l;
      GLL(vT_ws + kvbase + (size_t)d * 2048 + kt + ((vchunk ^ (d & 7)) << 3),
          ((unsigned short*)Vl[buf]) + slab * 512);
    }
  };

  stageK(0, 0); stageV(0, 0);
  int cur = 0;
  for (int it = 0; it < nt; ++it) {
    const int kt = it * 64;
    __syncthreads();
    if (it + 1 < nt) { stageK(cur ^ 1, kt + 64); stageV(cur ^ 1, kt + 64); }

    if (kt <= qb + 31) {
      f32x4 s[2][4];
#pragma unroll
      for (int qs = 0; qs < 2; ++qs)
#pragma unroll
        for (int t = 0; t < 4; ++t) s[qs][t] = f32x4{0.f, 0.f, 0.f, 0.f};
#pragma unroll
      for (int t = 0; t < 4; ++t) {
        const int key = t * 16 + q16;
#pragma unroll
        for (int c = 0; c < 4; ++c) {
          bf16x8 kf = *(const bf16x8*)&Kl[cur][key * 128 + (((c * 4 + g) ^ (key & 7)) << 3)];
          s[0][t] = __builtin_amdgcn_mfma_f32_16x16x32_bf16(kf, qf[0][c], s[0][t], 0, 0, 0);
          s[1][t] = __builtin_amdgcn_mfma_f32_16x16x32_bf16(kf, qf[1][c], s[1][t], 0, 0, 0);
        }
      }

#pragma unroll
      for (int qs = 0; qs < 2; ++qs) {
        const int qrow = qb + qs * 16 + q16;
        if (kt + 64 > qb + qs * 16) {
#pragma unroll
          for (int t = 0; t < 4; ++t)
#pragma unroll
            for (int r = 0; r < 4; ++r)
              if (kt + t * 16 + g * 4 + r > qrow) s[qs][t][r] = -1e30f;
        }
        float tm = s[qs][0][0];
#pragma unroll
        for (int t = 0; t < 4; ++t)
#pragma unroll
          for (int r = 0; r < 4; ++r) tm = fmaxf(tm, s[qs][t][r]);
        tm = fmaxf(tm, __shfl_xor(tm, 16));
        tm = fmaxf(tm, __shfl_xor(tm, 32));
        if (__any(tm > mrun[qs] + 8.0f)) {             // T13 defer-max
          const float mnew = fmaxf(mrun[qs], tm);
          const float fac = __expf(mrun[qs] - mnew);
          lrun[qs] *= fac;
          mrun[qs] = mnew;
          float fr0 = __shfl(fac, g * 4 + 0), fr1 = __shfl(fac, g * 4 + 1);
          float fr2 = __shfl(fac, g * 4 + 2), fr3 = __shfl(fac, g * 4 + 3);
#pragma unroll
          for (int n = 0; n < 8; ++n) {
            acc[qs][n][0] *= fr0; acc[qs][n][1] *= fr1;
            acc[qs][n][2] *= fr2; acc[qs][n][3] *= fr3;
          }
        }
        float ps = 0.f;
        unsigned pk[8];
#pragma unroll
        for (int t = 0; t < 4; ++t) {
          const float p0 = __expf(s[qs][t][0] - mrun[qs]);
          const float p1 = __expf(s[qs][t][1] - mrun[qs]);
          const float p2 = __expf(s[qs][t][2] - mrun[qs]);
          const float p3 = __expf(s[qs][t][3] - mrun[qs]);
          ps += (p0 + p1) + (p2 + p3);
          pk[t * 2]     = (unsigned)f2bf(p0) | ((unsigned)f2bf(p1) << 16);
          pk[t * 2 + 1] = (unsigned)f2bf(p2) | ((unsigned)f2bf(p3) << 16);
        }
        ps += __shfl_xor(ps, 16);
        ps += __shfl_xor(ps, 32);
        lrun[qs] += ps;
#pragma unroll
        for (int t = 0; t < 4; ++t) {
          const unsigned byteoff = (unsigned)(q16 * 128) +
              (((unsigned)(t * 32 + g * 8)) ^ ((unsigned)(q16 & 7) << 4));
          *(uint2*)((char*)&Pl[w][qs][0] + byteoff) = make_uint2(pk[t * 2], pk[t * 2 + 1]);
        }
      }

      asm volatile("s_waitcnt lgkmcnt(0)" ::: "memory");
      __builtin_amdgcn_sched_barrier(0);
#pragma unroll
      for (int ks = 0; ks < 2; ++ks) {
        const unsigned pcol = ((unsigned)(ks * 64 + g * 16)) ^ ((unsigned)(q16 & 7) << 4);
        bf16x8 pa0 = *(const bf16x8*)((char*)&Pl[w][0][0] + q16 * 128 + pcol);
        bf16x8 pa1 = *(const bf16x8*)((char*)&Pl[w][1][0] + q16 * 128 + pcol);
#pragma unroll
        for (int n = 0; n < 8; ++n) {
          const int d = n * 16 + q16;
          bf16x8 vf = *(const bf16x8*)&Vl[cur][d * 64 + (((ks * 4 + g) ^ (d & 7)) << 3)];
          acc[0][n] = __builtin_amdgcn_mfma_f32_16x16x32_bf16(pa0, vf, acc[0][n], 0, 0, 0);
          acc[1][n] = __builtin_amdgcn_mfma_f32_16x16x32_bf16(pa1, vf, acc[1][n], 0, 0, 0);
        }
      }
    }
    cur ^= 1;
  }

#pragma unroll
  for (int qs = 0; qs < 2; ++qs) {
    float rl[4];
#pragma unroll
    for (int r = 0; r < 4; ++r) rl[r] = 1.0f / __shfl(lrun[qs], g * 4 + r);
#pragma unroll
    for (int n = 0; n < 8; ++n) {
#pragma unroll
      for (int r = 0; r < 4; ++r) {
        const int q = qb + qs * 16 + g * 4 + r;
        const int d = n * 16 + q16;
        attnout[((size_t)(b * 2048 + q)) * 2048 + h * 128 + d] = f2bf(acc[qs][n][r] * rl[r]);
      }
    }
  }
}

extern "C" void kernel_launch(void* const* d_in, const int* in_sizes, int n_in,
                              void* d_out, int out_size, void* d_ws, size_t ws_size,
                              hipStream_t stream) {
  (void)in_sizes; (void)n_in; (void)out_size; (void)ws_size;
  const float* x    = (const float*)d_in[0];
  const float* fcos = (const float*)d_in[1];
  const float* fsin = (const float*)d_in[2];
  const float* Wqkv = (const float*)d_in[3];
  const float* Wout = (const float*)d_in[4];

  float* out   = (float*)d_out;
  float* y_out = out;
  float* k_out = out + (size_t)16777216;          // B*T*C
  float* v_out = out + (size_t)33554432;

  unsigned short* xb      = (unsigned short*)d_ws;     // 8192 x 2048
  unsigned short* wqkvT   = xb + 16777216;             // 6144 x 2048
  unsigned short* woutT   = wqkvT + 12582912;          // 2048 x 2048
  unsigned short* q_ws    = woutT + 4194304;           // (B,H,T,hd) pre-scaled
  unsigned short* k_ws    = q_ws + 16777216;           // (B,H,T,hd)
  unsigned short* vT_ws   = k_ws + 16777216;           // (B,H,hd,T)
  unsigned short* attnout = xb;                        // alias: x consumed by then

  cvt_x_kernel<<<16384, 256, 0, stream>>>(x, xb, 4194304);
  transpose_kernel<<<dim3(192, 64), dim3(32, 8), 0, stream>>>(Wqkv, wqkvT, 2048, 6144);
  transpose_kernel<<<dim3(64, 64), dim3(32, 8), 0, stream>>>(Wout, woutT, 2048, 2048);

  // GEMM1: 8192 x 6144 x 2048, fused RoPE/qkv epilogue. Grid 32x24=768 (%8==0).
  gemm8_kernel<1><<<768, 512, 0, stream>>>(
      xb, wqkvT, 2048, 6144, 31, 5,
      nullptr, fcos, fsin, q_ws, k_ws, vT_ws, k_out, v_out);

  attn_kernel<<<dim3(64, 16), 256, 0, stream>>>(q_ws, k_ws, vT_ws, attnout);

  // GEMM2: 8192 x 2048 x 2048 -> y. Grid 32x8=256 (%8==0).
  gemm8_kernel<0><<<256, 512, 0, stream>>>(
      attnout, woutT, 2048, 2048, 31, 5,
      y_out, nullptr, nullptr, nullptr, nullptr, nullptr, nullptr, nullptr);
}